// Round 12
// baseline (13003.563 us; speedup 1.0000x reference)
//
#include <hip/hip_runtime.h>

#define T_STEPS 25
#define BATCH   128
#define D_IN    2048
#define H_DIM   4096
#define C_DIM   1000
#define N_ALL   3200
#define GEMM_Q  320   // OpenBLAS SGEMM_DEFAULT_Q, SKYLAKEX path (verified bit-exact R7-R16)
#define P_K2048 7     // panels: 320x5, 224, 224
#define P_K4096 13    // panels: 320x11, 288, 288
#define WOT_LD  1024  // wo^T padded out-M (1000 -> 1024, pad rows zero)

typedef __attribute__((address_space(1))) const void gas_t;
typedef __attribute__((address_space(3))) void las_t;

// OpenBLAS level3 K-panel schedule (verified bit-exact R7):
__device__ __forceinline__ int panel_len(int rem) {
    return (rem >= 2 * GEMM_Q) ? GEMM_Q
         : (rem > GEMM_Q ? ((rem / 2 + 15) & ~15) : rem);
}

// ---------------- transpose (+optional mask premultiply, zero-pad): dst[K][MT] ----------------
// Mask entries are exactly 0/1, so w*m is the identical fp32 product the reference forms.
__global__ __launch_bounds__(256)
void tmask_k(float* __restrict__ dst, const float* __restrict__ src,
             const float* __restrict__ msk, int M, int K, int MT)
{
    __shared__ float t[32][33];
    const int tx = threadIdx.x, ty = threadIdx.y;
    const int k0 = blockIdx.x * 32, m0 = blockIdx.y * 32;
    #pragma unroll
    for (int i = 0; i < 4; ++i) {
        const int m = m0 + ty + 8 * i;
        float v = 0.f;
        if (m < M) {
            const size_t gi = (size_t)m * K + k0 + tx;
            v = src[gi];
            if (msk) v *= msk[gi];
        }
        t[ty + 8 * i][tx] = v;
    }
    __syncthreads();
    const int mc = m0 + tx;
    if (mc < MT) {
        #pragma unroll
        for (int i = 0; i < 4; ++i)
            dst[(size_t)(k0 + ty + 8 * i) * MT + mc] = t[tx][ty + 8 * i];
    }
}

// ---------------- 4-wave shared-B GEMM: block = 64m x 128b, wave = 16m x 128b, lane = 16m x 2c ----------------
// LDS-roofline redesign. Ledger for the old (8m x 4c) lane shape: 48B LDS / 32 MACs
// = 1.5 B/MAC -> LDS floor 61us at K=4096; measured 73us = 84% of the LDS pipe.
// The asymmetry never exploited: A is wave-uniform per 16-row group -> broadcast it
// through the SCALAR pipe (SMEM/K$), not LDS. New lane map: wave = 16m x 128c (same
// wave count -> 13 waves/CU preserved), lane owns 16 rows x 2 adjacent cols.
//   Per kk: A = 16 uniform floats, address derived from blockIdx/loop counter only
//   -> compiler emits s_load (scalar cache; zero LDS, zero VALU). B = ONE
//   ds_read_b64 at Bs[kk][lane*2]: 64 lanes x 8B = 512B unit-stride burst,
//   conflict-free. LDS = 8B / 32 MACs = 0.25 B/MAC -> LDS floor ~10us; VALU (27us)
//   is now the binding pipe.
// A needs NO LDS staging (VMEM = 8 B-insts/block/tile). Same memory values, same
// ascending-k fmaf chain per output element, same OpenBLAS panel folds -> bit-exact.
// Cadence per tile (R6-proven): [stage B(ti+1) -> buf^1 (2 insts/wave)] [compute ti]
// [__syncthreads]. part[p][m][b] = ascending-k fmaf chain per panel from zero;
// cross-panel folds ascend in the reduce kernels.
__global__ __launch_bounds__(256)
void gemm_w(const float* __restrict__ AT, const float* __restrict__ B,
            float* __restrict__ part, int MT, int K, int ldb, int n0)
{
#pragma clang fp reassociate(off)
    __shared__ __align__(16) float Bs[2][16][128];    // 16 KB block-shared B tile (dbuf)
    const int tid  = threadIdx.x;
    const int w    = tid >> 6;                        // wave 0..3
    const int lane = tid & 63;
    const int m0   = blockIdx.y * 64 + w * 16;        // wave's 16-row m tile
    const int p    = blockIdx.x;

    int pstart = 0, rem = K, pl = panel_len(K);
    for (int i = 0; i < p; ++i) { pstart += pl; rem -= pl; pl = panel_len(rem); }
    const int nt = pl >> 4;                           // 320/288/224 all /16

    float2 acc[16];
    #pragma unroll
    for (int r = 0; r < 16; ++r) acc[r] = make_float2(0.f, 0.f);

    // B stage (block-cooperative, R6-verified): wave w covers rows w*4..w*4+3 via
    // 2 insts; inst i: lanes 0-31 -> row w*4+2i col (lane&31)*4, lanes 32-63 -> +1
    const float* bsrc = B + (size_t)(pstart + w * 4 + (lane >> 5)) * ldb + n0 + (lane & 31) * 4;
    // A scalar base (wave-uniform): row k of AT, cols m0..m0+15
    const float* abase = AT + (size_t)pstart * MT + m0;

    {   // prologue: stage B tile 0
        __builtin_amdgcn_global_load_lds((gas_t*)bsrc,
                                         (las_t*)&Bs[0][w * 4][0], 16, 0, 0);
        __builtin_amdgcn_global_load_lds((gas_t*)(bsrc + 2 * (size_t)ldb),
                                         (las_t*)&Bs[0][w * 4 + 2][0], 16, 0, 0);
    }
    __syncthreads();

    for (int ti = 0; ti < nt; ++ti) {
        const int bf = ti & 1;
        // ---- stage B(ti+1) into buf^1 (2 insts/wave; lands before the sync) ----
        if (ti + 1 < nt) {
            const float* b2 = bsrc + (size_t)(ti + 1) * 16 * ldb;
            __builtin_amdgcn_global_load_lds((gas_t*)b2,
                                             (las_t*)&Bs[bf ^ 1][w * 4][0], 16, 0, 0);
            __builtin_amdgcn_global_load_lds((gas_t*)(b2 + 2 * (size_t)ldb),
                                             (las_t*)&Bs[bf ^ 1][w * 4 + 2][0], 16, 0, 0);
        }
        // ---- compute tile ti: 16 ascending k-steps; 32 fmaf per lane per kk ----
        const float* atile = abase + (size_t)ti * 16 * MT;   // uniform
        #pragma unroll
        for (int kk = 0; kk < 16; ++kk) {
            const float* ar = atile + (size_t)kk * MT;       // uniform -> s_load
            const float2 bv = *(const float2*)&Bs[bf][kk][lane * 2];
            #pragma unroll
            for (int r = 0; r < 16; ++r) {
                const float av = ar[r];                      // scalar broadcast
                acc[r].x = fmaf(av, bv.x, acc[r].x);
                acc[r].y = fmaf(av, bv.y, acc[r].y);
            }
        }
        // vmcnt(0)+lgkmcnt(0)+barrier: staging(ti+1) landed; all waves done reading buf
        __syncthreads();
    }

    #pragma unroll
    for (int r = 0; r < 16; ++r)
        *(float2*)&part[((size_t)p * MT + m0 + r) * BATCH + lane * 2] = acc[r];
}

// ---------------- LIF (ops mirror np exactly; verified R7-R16) ----------------
__device__ __forceinline__ float lif1e(float c, float& m)
{
    const float r = (m > 1.0f) ? 1.0f : 0.0f;
    const float mn = __fsub_rn(__fadd_rn(__fmul_rn(0.95f, m), c), r);
    m = mn;
    return (mn > 1.0f) ? 1.0f : 0.0f;
}

// fold P panels ascending (one __fadd_rn each) + bias + LIF; float4 per thread
__global__ __launch_bounds__(256)
void reduce_lif4(const float* __restrict__ part, int P, int Mdim,
                 const float* __restrict__ bias, float* __restrict__ mem,
                 float* __restrict__ spk)
{
#pragma clang fp reassociate(off)
    const int idx4 = blockIdx.x * 256 + threadIdx.x;
    const int idx = idx4 * 4;
    const size_t stride = (size_t)Mdim * BATCH;
    float4 tot = *(const float4*)&part[idx];
    for (int z = 1; z < P; ++z) {
        const float4 pv = *(const float4*)&part[(size_t)z * stride + idx];
        tot.x = __fadd_rn(tot.x, pv.x); tot.y = __fadd_rn(tot.y, pv.y);
        tot.z = __fadd_rn(tot.z, pv.z); tot.w = __fadd_rn(tot.w, pv.w);
    }
    const float bb = bias[idx >> 7];
    float4 mm = *(float4*)&mem[idx];
    float4 sp;
    sp.x = lif1e(__fadd_rn(tot.x, bb), mm.x);
    sp.y = lif1e(__fadd_rn(tot.y, bb), mm.y);
    sp.z = lif1e(__fadd_rn(tot.z, bb), mm.z);
    sp.w = lif1e(__fadd_rn(tot.w, bb), mm.w);
    *(float4*)&mem[idx] = mm;
    *(float4*)&spk[idx] = sp;
}

// out-layer fold: partials are [P][Mpad][BATCH] (Mpad=1024 zero-padded); C_DIM rows live
__global__ __launch_bounds__(256)
void reduce_lif_out4(const float* __restrict__ part, int P, int Mpad,
                     const float* __restrict__ bias, float* __restrict__ mem,
                     float* __restrict__ out)
{
#pragma clang fp reassociate(off)
    const int idx4 = blockIdx.x * 256 + threadIdx.x;
    if (idx4 >= (C_DIM * BATCH) / 4) return;
    const int idx = idx4 * 4;
    const int cc = idx >> 7, b = idx & 127;
    const size_t stride = (size_t)Mpad * BATCH;
    float4 tot = *(const float4*)&part[idx];
    for (int z = 1; z < P; ++z) {
        const float4 pv = *(const float4*)&part[(size_t)z * stride + idx];
        tot.x = __fadd_rn(tot.x, pv.x); tot.y = __fadd_rn(tot.y, pv.y);
        tot.z = __fadd_rn(tot.z, pv.z); tot.w = __fadd_rn(tot.w, pv.w);
    }
    const float bb = bias[cc];
    float4 mm = *(float4*)&mem[idx];
    float s;
    s = lif1e(__fadd_rn(tot.x, bb), mm.x); if (s > 0.f) out[(size_t)(b+0) * C_DIM + cc] += 1.0f;
    s = lif1e(__fadd_rn(tot.y, bb), mm.y); if (s > 0.f) out[(size_t)(b+1) * C_DIM + cc] += 1.0f;
    s = lif1e(__fadd_rn(tot.z, bb), mm.z); if (s > 0.f) out[(size_t)(b+2) * C_DIM + cc] += 1.0f;
    s = lif1e(__fadd_rn(tot.w, bb), mm.w); if (s > 0.f) out[(size_t)(b+3) * C_DIM + cc] += 1.0f;
    *(float4*)&mem[idx] = mm;
}

// ---------------- host ----------------
extern "C" void kernel_launch(void* const* d_in, const int* in_sizes, int n_in,
                              void* d_out, int out_size, void* d_ws, size_t ws_size,
                              hipStream_t stream)
{
    const float* x  = (const float*)d_in[0];
    const float* w1 = (const float*)d_in[1];
    const float* b1 = (const float*)d_in[2];
    const float* m1 = (const float*)d_in[3];
    const float* w2 = (const float*)d_in[4];
    const float* b2 = (const float*)d_in[5];
    const float* m2 = (const float*)d_in[6];
    const float* w3 = (const float*)d_in[7];
    const float* b3 = (const float*)d_in[8];
    const float* m3 = (const float*)d_in[9];
    const float* wo = (const float*)d_in[10];
    const float* bo = (const float*)d_in[11];
    float* out = (float*)d_out;
    float* ws  = (float*)d_ws;
    (void)in_sizes; (void)n_in; (void)ws_size;

    const size_t HB = (size_t)H_DIM * BATCH;        // 524288
    const size_t CB = (size_t)C_DIM * BATCH;        // 128000

    // ---- ws layout (floats) — total ≈ 252 MB (verified fits R12-R16) ----
    size_t off = 0;
    const size_t MEM1 = off; off += HB;
    const size_t MEM2 = off; off += HB;
    const size_t MEM3 = off; off += HB;
    const size_t MEMO = off; off += CB;
    const size_t stateFloats = off;                 // zeroed every call
    const size_t SPK1 = off; off += HB;
    const size_t SPK2 = off; off += HB;
    const size_t SPK3 = off; off += HB;
    const size_t PART = off; off += (size_t)P_K4096 * HB;       // 13 x [4096][128]
    const size_t EWT1 = off; off += (size_t)D_IN * H_DIM;       // [2048][4096]
    const size_t EWT2 = off; off += (size_t)H_DIM * H_DIM;      // [4096][4096]
    const size_t EWT3 = off; off += (size_t)H_DIM * H_DIM;
    const size_t WOT  = off; off += (size_t)H_DIM * WOT_LD;     // [4096][1024]
    const size_t XT   = off; off += (size_t)D_IN * N_ALL;       // [2048][3200]

    hipMemsetAsync(d_ws, 0, stateFloats * sizeof(float), stream);
    hipMemsetAsync(d_out, 0, (size_t)out_size * sizeof(float), stream);

    // ---- one-time transposes (premask fused; bit-exact products) ----
    {
        dim3 tb(32, 8);
        tmask_k<<<dim3(D_IN / 32, H_DIM / 32), tb, 0, stream>>>(ws + EWT1, w1, m1, H_DIM, D_IN, H_DIM);
        tmask_k<<<dim3(H_DIM / 32, H_DIM / 32), tb, 0, stream>>>(ws + EWT2, w2, m2, H_DIM, H_DIM, H_DIM);
        tmask_k<<<dim3(H_DIM / 32, H_DIM / 32), tb, 0, stream>>>(ws + EWT3, w3, m3, H_DIM, H_DIM, H_DIM);
        tmask_k<<<dim3(H_DIM / 32, WOT_LD / 32), tb, 0, stream>>>(ws + WOT, wo, nullptr, C_DIM, H_DIM, WOT_LD);
        tmask_k<<<dim3(D_IN / 32, N_ALL / 32), tb, 0, stream>>>(ws + XT, x, nullptr, N_ALL, D_IN, N_ALL);
    }

    const dim3 g1(P_K2048, H_DIM / 64);             // 7 x 64 = 448 4-wave blocks
    const dim3 g23(P_K4096, H_DIM / 64);            // 13 x 64 = 832 4-wave blocks
    const dim3 go(P_K4096, WOT_LD / 64);            // 13 x 16 = 208 4-wave blocks
    const int gLif4  = (int)(HB / 4 / 256);         // 512
    const int gLifO4 = (int)((CB / 4 + 255) / 256); // 125

    for (int t = 0; t < T_STEPS; ++t) {
        // layer 1: AT = EWT1 [2048][4096], B = XT [2048][3200] cols t*128..
        gemm_w<<<g1, 256, 0, stream>>>(ws + EWT1, ws + XT, ws + PART,
                                       H_DIM, D_IN, N_ALL, t * BATCH);
        reduce_lif4<<<gLif4, 256, 0, stream>>>(ws + PART, P_K2048, H_DIM, b1, ws + MEM1, ws + SPK1);

        // layer 2
        gemm_w<<<g23, 256, 0, stream>>>(ws + EWT2, ws + SPK1, ws + PART,
                                        H_DIM, H_DIM, BATCH, 0);
        reduce_lif4<<<gLif4, 256, 0, stream>>>(ws + PART, P_K4096, H_DIM, b2, ws + MEM2, ws + SPK2);

        // layer 3
        gemm_w<<<g23, 256, 0, stream>>>(ws + EWT3, ws + SPK2, ws + PART,
                                        H_DIM, H_DIM, BATCH, 0);
        reduce_lif4<<<gLif4, 256, 0, stream>>>(ws + PART, P_K4096, H_DIM, b3, ws + MEM3, ws + SPK3);

        // output layer (WOT zero-padded to 1024 rows)
        gemm_w<<<go, 256, 0, stream>>>(ws + WOT, ws + SPK3, ws + PART,
                                       WOT_LD, H_DIM, BATCH, 0);
        reduce_lif_out4<<<gLifO4, 256, 0, stream>>>(ws + PART, P_K4096, WOT_LD, bo, ws + MEMO, out);
    }
}

// Round 13
// 4665.934 us; speedup vs baseline: 2.7869x; 2.7869x over previous
//
#include <hip/hip_runtime.h>

#define T_STEPS 25
#define BATCH   128
#define D_IN    2048
#define H_DIM   4096
#define C_DIM   1000
#define N_ALL   3200
#define GEMM_Q  320   // OpenBLAS SGEMM_DEFAULT_Q, SKYLAKEX path (verified bit-exact R7-R16)
#define P_K2048 7     // panels: 320x5, 224, 224
#define P_K4096 13    // panels: 320x11, 288, 288
#define WOT_LD  1024  // wo^T padded out-M (1000 -> 1024, pad rows zero)

typedef __attribute__((address_space(1))) const void gas_t;
typedef __attribute__((address_space(3))) void las_t;

// OpenBLAS level3 K-panel schedule (verified bit-exact R7):
__device__ __forceinline__ int panel_len(int rem) {
    return (rem >= 2 * GEMM_Q) ? GEMM_Q
         : (rem > GEMM_Q ? ((rem / 2 + 15) & ~15) : rem);
}

// ---------------- transpose (+optional mask premultiply, zero-pad): dst[K][MT] ----------------
__global__ __launch_bounds__(256)
void tmask_k(float* __restrict__ dst, const float* __restrict__ src,
             const float* __restrict__ msk, int M, int K, int MT)
{
    __shared__ float t[32][33];
    const int tx = threadIdx.x, ty = threadIdx.y;
    const int k0 = blockIdx.x * 32, m0 = blockIdx.y * 32;
    #pragma unroll
    for (int i = 0; i < 4; ++i) {
        const int m = m0 + ty + 8 * i;
        float v = 0.f;
        if (m < M) {
            const size_t gi = (size_t)m * K + k0 + tx;
            v = src[gi];
            if (msk) v *= msk[gi];
        }
        t[ty + 8 * i][tx] = v;
    }
    __syncthreads();
    const int mc = m0 + tx;
    if (mc < MT) {
        #pragma unroll
        for (int i = 0; i < 4; ++i)
            dst[(size_t)(k0 + ty + 8 * i) * MT + mc] = t[tx][ty + 8 * i];
    }
}

// ---------------- R10-verified GEMM body (best: 73.4us K=4096, 0 conflicts, bit-exact) ----------------
// block = 64m x 128b, wave = 16m, lane = 8m x 4b. B tile (16k x 128c, 8KB) staged once
// per 4-wave block via global_load_lds; A tile wave-private. Software-pipelined 16-k
// inner loop (register rotation). Cadence: [stage ti+1 -> buf^1] [compute ti]
// [__syncthreads]. part[p][m][b] = ascending-k fmaf chain per panel from zero;
// cross-panel folds ascend in the reduce kernels (OpenBLAS-exact ordering).
#define FMAQ(AS, R)                                                   \
    acc[R].x = fmaf(AS, bv.x, acc[R].x);                              \
    acc[R].y = fmaf(AS, bv.y, acc[R].y);                              \
    acc[R].z = fmaf(AS, bv.z, acc[R].z);                              \
    acc[R].w = fmaf(AS, bv.w, acc[R].w);

typedef float BsT[16][128];
typedef float AsT[2][16][16];

__device__ __forceinline__ void gemm_body(BsT* Bs, AsT* As,
                                          const float* __restrict__ AT,
                                          const float* __restrict__ B,
                                          float* __restrict__ part,
                                          int MT, int K, int ldb, int n0,
                                          int p, int my)
{
#pragma clang fp reassociate(off)
    const int tid  = threadIdx.x;
    const int w    = tid >> 6;                        // wave 0..3
    const int lane = tid & 63;
    const int mg   = lane >> 5;                       // 0/1: m-half within wave tile
    const int lc   = lane & 31;                       // b-col quad
    const int m0   = my * 64 + w * 16;                // wave's 16-row m tile

    int pstart = 0, rem = K, pl = panel_len(K);
    for (int i = 0; i < p; ++i) { pstart += pl; rem -= pl; pl = panel_len(rem); }
    const int nt = pl >> 4;                           // 320/288/224 all /16

    float4 acc[8];
    #pragma unroll
    for (int r = 0; r < 8; ++r) acc[r] = make_float4(0.f, 0.f, 0.f, 0.f);

    const int akr = lane >> 2, amq = (lane & 3) * 4;
    const float* ap = AT + (size_t)(pstart + akr) * MT + m0 + amq;
    const float* bsrc = B + (size_t)(pstart + w * 4 + (lane >> 5)) * ldb + n0 + lc * 4;

    {   // prologue: stage tile 0
        __builtin_amdgcn_global_load_lds((gas_t*)ap, (las_t*)&As[w][0][0][0], 16, 0, 0);
        __builtin_amdgcn_global_load_lds((gas_t*)bsrc,
                                         (las_t*)&Bs[0][w * 4][0], 16, 0, 0);
        __builtin_amdgcn_global_load_lds((gas_t*)(bsrc + 2 * (size_t)ldb),
                                         (las_t*)&Bs[0][w * 4 + 2][0], 16, 0, 0);
    }
    __syncthreads();

    for (int ti = 0; ti < nt; ++ti) {
        const int bf = ti & 1;
        if (ti + 1 < nt) {
            const float* a2 = ap + (size_t)(ti + 1) * 16 * MT;
            const float* b2 = bsrc + (size_t)(ti + 1) * 16 * ldb;
            __builtin_amdgcn_global_load_lds((gas_t*)a2, (las_t*)&As[w][bf ^ 1][0][0], 16, 0, 0);
            __builtin_amdgcn_global_load_lds((gas_t*)b2,
                                             (las_t*)&Bs[bf ^ 1][w * 4][0], 16, 0, 0);
            __builtin_amdgcn_global_load_lds((gas_t*)(b2 + 2 * (size_t)ldb),
                                             (las_t*)&Bs[bf ^ 1][w * 4 + 2][0], 16, 0, 0);
        }
        {   // software-pipelined 16 ascending k-steps (R10 body, values/order = R6)
            float4 a0 = *(const float4*)&As[w][bf][0][mg * 8];
            float4 a1 = *(const float4*)&As[w][bf][0][mg * 8 + 4];
            float4 bv = *(const float4*)&Bs[bf][0][lc * 4];
            #pragma unroll
            for (int kk = 0; kk < 16; ++kk) {
                float4 na0, na1, nbv;
                if (kk < 15) {
                    na0 = *(const float4*)&As[w][bf][kk + 1][mg * 8];
                    na1 = *(const float4*)&As[w][bf][kk + 1][mg * 8 + 4];
                    nbv = *(const float4*)&Bs[bf][kk + 1][lc * 4];
                }
                FMAQ(a0.x, 0) FMAQ(a0.y, 1) FMAQ(a0.z, 2) FMAQ(a0.w, 3)
                FMAQ(a1.x, 4) FMAQ(a1.y, 5) FMAQ(a1.z, 6) FMAQ(a1.w, 7)
                if (kk < 15) { a0 = na0; a1 = na1; bv = nbv; }
            }
        }
        __syncthreads();
    }

    const int mrow0 = m0 + mg * 8;
    #pragma unroll
    for (int r = 0; r < 8; ++r)
        *(float4*)&part[((size_t)p * MT + mrow0 + r) * BATCH + lc * 4] = acc[r];
}

__global__ __launch_bounds__(256)
void gemm_w(const float* __restrict__ AT, const float* __restrict__ B,
            float* __restrict__ part, int MT, int K, int ldb, int n0)
{
    __shared__ __align__(16) float BsS[2][16][128];
    __shared__ __align__(16) float AsS[4][2][16][16];
    gemm_body((BsT*)BsS, (AsT*)AsS, AT, B, part, MT, K, ldb, n0,
              blockIdx.x, blockIdx.y);
}

// Merged dispatch: OUT(t) (208 blocks, alone = 0.81 blocks/CU, >=48 CUs idle) fused
// with L1(t+1) (448 blocks). Data-independent: OUT needs spk3(t), L1 needs only x.
// 656 blocks -> 2.56/CU, idle CUs filled. Branch is blockIdx-uniform -> barriers safe.
__global__ __launch_bounds__(256)
void gemm_pair(const float* __restrict__ ATo, const float* __restrict__ Bo,
               float* __restrict__ po, int MTo, int Ko, int ldbo, int n0o, int nbo, int npo,
               const float* __restrict__ AT1, const float* __restrict__ B1,
               float* __restrict__ p1, int MT1, int K1, int ldb1, int n01, int np1)
{
    __shared__ __align__(16) float BsS[2][16][128];
    __shared__ __align__(16) float AsS[4][2][16][16];
    const int bid = blockIdx.x;
    if (bid < nbo)
        gemm_body((BsT*)BsS, (AsT*)AsS, ATo, Bo, po, MTo, Ko, ldbo, n0o,
                  bid % npo, bid / npo);
    else
        gemm_body((BsT*)BsS, (AsT*)AsS, AT1, B1, p1, MT1, K1, ldb1, n01,
                  (bid - nbo) % np1, (bid - nbo) / np1);
}

// ---------------- LIF (ops mirror np exactly; verified R7-R16) ----------------
__device__ __forceinline__ float lif1e(float c, float& m)
{
    const float r = (m > 1.0f) ? 1.0f : 0.0f;
    const float mn = __fsub_rn(__fadd_rn(__fmul_rn(0.95f, m), c), r);
    m = mn;
    return (mn > 1.0f) ? 1.0f : 0.0f;
}

__device__ __forceinline__ void red_lif4_body(int bid, const float* __restrict__ part,
                                              int P, int Mdim, const float* __restrict__ bias,
                                              float* __restrict__ mem, float* __restrict__ spk)
{
#pragma clang fp reassociate(off)
    const int idx4 = bid * 256 + threadIdx.x;
    const int idx = idx4 * 4;
    const size_t stride = (size_t)Mdim * BATCH;
    float4 tot = *(const float4*)&part[idx];
    for (int z = 1; z < P; ++z) {
        const float4 pv = *(const float4*)&part[(size_t)z * stride + idx];
        tot.x = __fadd_rn(tot.x, pv.x); tot.y = __fadd_rn(tot.y, pv.y);
        tot.z = __fadd_rn(tot.z, pv.z); tot.w = __fadd_rn(tot.w, pv.w);
    }
    const float bb = bias[idx >> 7];
    float4 mm = *(float4*)&mem[idx];
    float4 sp;
    sp.x = lif1e(__fadd_rn(tot.x, bb), mm.x);
    sp.y = lif1e(__fadd_rn(tot.y, bb), mm.y);
    sp.z = lif1e(__fadd_rn(tot.z, bb), mm.z);
    sp.w = lif1e(__fadd_rn(tot.w, bb), mm.w);
    *(float4*)&mem[idx] = mm;
    *(float4*)&spk[idx] = sp;
}

__device__ __forceinline__ void red_lifo_body(int bid, const float* __restrict__ part,
                                              int P, int Mpad, const float* __restrict__ bias,
                                              float* __restrict__ mem, float* __restrict__ out)
{
#pragma clang fp reassociate(off)
    const int idx4 = bid * 256 + threadIdx.x;
    if (idx4 >= (C_DIM * BATCH) / 4) return;
    const int idx = idx4 * 4;
    const int cc = idx >> 7, b = idx & 127;
    const size_t stride = (size_t)Mpad * BATCH;
    float4 tot = *(const float4*)&part[idx];
    for (int z = 1; z < P; ++z) {
        const float4 pv = *(const float4*)&part[(size_t)z * stride + idx];
        tot.x = __fadd_rn(tot.x, pv.x); tot.y = __fadd_rn(tot.y, pv.y);
        tot.z = __fadd_rn(tot.z, pv.z); tot.w = __fadd_rn(tot.w, pv.w);
    }
    const float bb = bias[cc];
    float4 mm = *(float4*)&mem[idx];
    float s;
    s = lif1e(__fadd_rn(tot.x, bb), mm.x); if (s > 0.f) out[(size_t)(b+0) * C_DIM + cc] += 1.0f;
    s = lif1e(__fadd_rn(tot.y, bb), mm.y); if (s > 0.f) out[(size_t)(b+1) * C_DIM + cc] += 1.0f;
    s = lif1e(__fadd_rn(tot.z, bb), mm.z); if (s > 0.f) out[(size_t)(b+2) * C_DIM + cc] += 1.0f;
    s = lif1e(__fadd_rn(tot.w, bb), mm.w); if (s > 0.f) out[(size_t)(b+3) * C_DIM + cc] += 1.0f;
    *(float4*)&mem[idx] = mm;
}

__global__ __launch_bounds__(256)
void reduce_lif4(const float* __restrict__ part, int P, int Mdim,
                 const float* __restrict__ bias, float* __restrict__ mem,
                 float* __restrict__ spk)
{ red_lif4_body(blockIdx.x, part, P, Mdim, bias, mem, spk); }

__global__ __launch_bounds__(256)
void reduce_lif_out4(const float* __restrict__ part, int P, int Mpad,
                     const float* __restrict__ bias, float* __restrict__ mem,
                     float* __restrict__ out)
{ red_lifo_body(blockIdx.x, part, P, Mpad, bias, mem, out); }

// red1(t) (512 blocks) fused with redO(t-1) (125 blocks) - independent buffers.
__global__ __launch_bounds__(256)
void reduce_pair(const float* __restrict__ part, int P, int Mdim,
                 const float* __restrict__ bias, float* __restrict__ mem,
                 float* __restrict__ spk,
                 const float* __restrict__ parto, int Po, int Mpad,
                 const float* __restrict__ biaso, float* __restrict__ memo,
                 float* __restrict__ outp, int nb1)
{
    if ((int)blockIdx.x < nb1)
        red_lif4_body(blockIdx.x, part, P, Mdim, bias, mem, spk);
    else
        red_lifo_body(blockIdx.x - nb1, parto, Po, Mpad, biaso, memo, outp);
}

// ---------------- host ----------------
extern "C" void kernel_launch(void* const* d_in, const int* in_sizes, int n_in,
                              void* d_out, int out_size, void* d_ws, size_t ws_size,
                              hipStream_t stream)
{
    const float* x  = (const float*)d_in[0];
    const float* w1 = (const float*)d_in[1];
    const float* b1 = (const float*)d_in[2];
    const float* m1 = (const float*)d_in[3];
    const float* w2 = (const float*)d_in[4];
    const float* b2 = (const float*)d_in[5];
    const float* m2 = (const float*)d_in[6];
    const float* w3 = (const float*)d_in[7];
    const float* b3 = (const float*)d_in[8];
    const float* m3 = (const float*)d_in[9];
    const float* wo = (const float*)d_in[10];
    const float* bo = (const float*)d_in[11];
    float* out = (float*)d_out;
    float* ws  = (float*)d_ws;
    (void)in_sizes; (void)n_in; (void)ws_size;

    const size_t HB = (size_t)H_DIM * BATCH;        // 524288
    const size_t CB = (size_t)C_DIM * BATCH;        // 128000

    // ---- ws layout (floats) — same footprint as R10 (verified fits) ----
    size_t off = 0;
    const size_t MEM1 = off; off += HB;
    const size_t MEM2 = off; off += HB;
    const size_t MEM3 = off; off += HB;
    const size_t MEMO = off; off += CB;
    const size_t stateFloats = off;                 // zeroed every call
    const size_t SPK1 = off; off += HB;
    const size_t SPK2 = off; off += HB;
    const size_t SPK3 = off; off += HB;
    const size_t PART = off; off += (size_t)P_K4096 * HB;       // 13 x [4096][128]
    // OUT partials live in PART slots 7..12 (L1 uses slots 0..6; L2/L3 overwrite all
    // 13 slots only AFTER redO consumed PARTO - order verified in the loop below).
    const size_t PARTO = PART + (size_t)P_K2048 * HB;           // 13 x [1024][128] = 1.7M < 3.1M floats
    const size_t EWT1 = off; off += (size_t)D_IN * H_DIM;       // [2048][4096]
    const size_t EWT2 = off; off += (size_t)H_DIM * H_DIM;      // [4096][4096]
    const size_t EWT3 = off; off += (size_t)H_DIM * H_DIM;
    const size_t WOT  = off; off += (size_t)H_DIM * WOT_LD;     // [4096][1024]
    const size_t XT   = off; off += (size_t)D_IN * N_ALL;       // [2048][3200]

    hipMemsetAsync(d_ws, 0, stateFloats * sizeof(float), stream);
    hipMemsetAsync(d_out, 0, (size_t)out_size * sizeof(float), stream);

    // ---- one-time transposes (premask fused; bit-exact products) ----
    {
        dim3 tb(32, 8);
        tmask_k<<<dim3(D_IN / 32, H_DIM / 32), tb, 0, stream>>>(ws + EWT1, w1, m1, H_DIM, D_IN, H_DIM);
        tmask_k<<<dim3(H_DIM / 32, H_DIM / 32), tb, 0, stream>>>(ws + EWT2, w2, m2, H_DIM, H_DIM, H_DIM);
        tmask_k<<<dim3(H_DIM / 32, H_DIM / 32), tb, 0, stream>>>(ws + EWT3, w3, m3, H_DIM, H_DIM, H_DIM);
        tmask_k<<<dim3(H_DIM / 32, WOT_LD / 32), tb, 0, stream>>>(ws + WOT, wo, nullptr, C_DIM, H_DIM, WOT_LD);
        tmask_k<<<dim3(D_IN / 32, N_ALL / 32), tb, 0, stream>>>(ws + XT, x, nullptr, N_ALL, D_IN, N_ALL);
    }

    const dim3 g1(P_K2048, H_DIM / 64);             // 7 x 64 = 448 4-wave blocks
    const dim3 g23(P_K4096, H_DIM / 64);            // 13 x 64 = 832 4-wave blocks
    const dim3 go(P_K4096, WOT_LD / 64);            // 13 x 16 = 208 4-wave blocks
    const int gLif4  = (int)(HB / 4 / 256);         // 512
    const int gLifO4 = (int)((CB / 4 + 255) / 256); // 125
    const int NB_OUT = P_K4096 * (WOT_LD / 64);     // 208
    const int NB_L1  = P_K2048 * (H_DIM / 64);      // 448

    // L1(0)
    gemm_w<<<g1, 256, 0, stream>>>(ws + EWT1, ws + XT, ws + PART, H_DIM, D_IN, N_ALL, 0);

    for (int t = 0; t < T_STEPS; ++t) {
        // red1(t) [reads PART slots 0..6 from L1(t)] + redO(t-1) [reads PARTO from
        // gemm_pair(t-1)] - both precede L2(t), which overwrites PART 0..12.
        if (t == 0)
            reduce_lif4<<<gLif4, 256, 0, stream>>>(ws + PART, P_K2048, H_DIM, b1, ws + MEM1, ws + SPK1);
        else
            reduce_pair<<<gLif4 + gLifO4, 256, 0, stream>>>(
                ws + PART, P_K2048, H_DIM, b1, ws + MEM1, ws + SPK1,
                ws + PARTO, P_K4096, WOT_LD, bo, ws + MEMO, out, gLif4);

        // layer 2
        gemm_w<<<g23, 256, 0, stream>>>(ws + EWT2, ws + SPK1, ws + PART, H_DIM, H_DIM, BATCH, 0);
        reduce_lif4<<<gLif4, 256, 0, stream>>>(ws + PART, P_K4096, H_DIM, b2, ws + MEM2, ws + SPK2);

        // layer 3
        gemm_w<<<g23, 256, 0, stream>>>(ws + EWT3, ws + SPK2, ws + PART, H_DIM, H_DIM, BATCH, 0);
        reduce_lif4<<<gLif4, 256, 0, stream>>>(ws + PART, P_K4096, H_DIM, b3, ws + MEM3, ws + SPK3);

        // OUT(t) [writes PARTO = PART slots 7..12 region, AFTER red3(t) consumed them]
        // merged with L1(t+1) [writes PART slots 0..6, consumed by red1(t+1)].
        if (t + 1 < T_STEPS)
            gemm_pair<<<NB_OUT + NB_L1, 256, 0, stream>>>(
                ws + WOT, ws + SPK3, ws + PARTO, WOT_LD, H_DIM, BATCH, 0, NB_OUT, P_K4096,
                ws + EWT1, ws + XT, ws + PART, H_DIM, D_IN, N_ALL, (t + 1) * BATCH, P_K2048);
        else
            gemm_w<<<go, 256, 0, stream>>>(ws + WOT, ws + SPK3, ws + PARTO, WOT_LD, H_DIM, BATCH, 0);
    }
    // redO(T-1)
    reduce_lif_out4<<<gLifO4, 256, 0, stream>>>(ws + PARTO, P_K4096, WOT_LD, bo, ws + MEMO, out);
}